// Round 3
// baseline (386.035 us; speedup 1.0000x reference)
//
#include <hip/hip_runtime.h>
#include <math.h>

// SpectralBias: B=1,H=16,L=2048,DH=64, M=2 modes, K=6 freqs, HIDDEN=128, OUT=9
// out[h,i,j] = mask(i>=j) * ( sum_k C[h,i,k] cos(w_k (i-j)) + S[h,i,k] sin(w_k (i-j))
//                             - b0[h,i] - slope[h,i]/64 * (i-j) )

typedef float f32x4_ __attribute__((ext_vector_type(4)));   // native vec type for nontemporal store

struct BiasParams {
    float omg[6];   // omega_k (np.logspace(..).astype(f32))
    float omg2[6];  // omega_k^2
    float cw[6];    // cos(omega_k)
    float sw[6];    // sin(omega_k)
    float cmn[6];   // mean_d cos(omega_k d), d in [0,2048)  (host, double prec)
    float smn[6];   // mean_d sin(omega_k d)
};

__device__ __forceinline__ float sigmoidf_(float x) { return 1.0f / (1.0f + expf(-x)); }
__device__ __forceinline__ float softplusf_(float x) {
    return fmaxf(x, 0.0f) + log1pf(expf(-fabsf(x)));   // stable, matches jax.nn.softplus
}

// ---------------- Kernel 1: per-query MLP -> {C[6], S[6], b0, slope/64} ----------------
// 512 blocks x 256 threads; 64 queries/block (lane = query), wave w owns hidden [32w,32w+32).
// w1/b1/w2 are read at wave-uniform addresses -> scalar loads; q lives in 64 VGPRs.
__global__ __launch_bounds__(256) void sb_coef_kernel(
    const float* __restrict__ q,  const float* __restrict__ w1,
    const float* __restrict__ b1, const float* __restrict__ w2,
    const float* __restrict__ b2, float* __restrict__ ws, BiasParams P)
{
    __shared__ float pl[256 * 13];     // layer-2 partials [4 waves][64 q][13]
    const int t    = threadIdx.x;
    const int lane = t & 63;
    const int w    = t >> 6;
    const int qid  = (blockIdx.x << 6) + lane;

    // per-lane query row -> registers
    float qv[64];
    {
        const float4* qr = (const float4*)(q + ((size_t)qid << 6));
        #pragma unroll
        for (int j = 0; j < 16; ++j) {
            float4 v = qr[j];
            qv[4*j+0] = v.x; qv[4*j+1] = v.y; qv[4*j+2] = v.z; qv[4*j+3] = v.w;
        }
    }

    const int h0 = __builtin_amdgcn_readfirstlane(w << 5);   // wave-uniform
    const float* __restrict__ w1u = w1 + (size_t)h0 * 64;

    float part[9];
    #pragma unroll
    for (int o = 0; o < 9; ++o) part[o] = 0.f;

    #pragma unroll 4
    for (int h = 0; h < 32; ++h) {
        const float* __restrict__ wr = w1u + h * 64;         // uniform row
        float a0 = 0.f, a1 = 0.f, a2 = 0.f, a3 = 0.f;
        #pragma unroll
        for (int d = 0; d < 64; d += 4) {
            a0 = fmaf(qv[d+0], wr[d+0], a0);
            a1 = fmaf(qv[d+1], wr[d+1], a1);
            a2 = fmaf(qv[d+2], wr[d+2], a2);
            a3 = fmaf(qv[d+3], wr[d+3], a3);
        }
        float a = ((a0 + a1) + (a2 + a3)) + b1[h0 + h];
        a = a * sigmoidf_(a);                                // SiLU
        #pragma unroll
        for (int o = 0; o < 9; ++o)
            part[o] = fmaf(a, w2[o * 128 + h0 + h], part[o]); // uniform scalar
    }

    #pragma unroll
    for (int o = 0; o < 9; ++o) pl[t * 13 + o] = part[o];    // stride 13: conflict-free
    __syncthreads();

    if (w == 0) {
        float y[9];
        #pragma unroll
        for (int o = 0; o < 9; ++o)
            y[o] = b2[o] + pl[lane * 13 + o] + pl[(64 + lane) * 13 + o]
                 + pl[(128 + lane) * 13 + o] + pl[(192 + lane) * 13 + o];

        float C[6], S[6];
        #pragma unroll
        for (int k = 0; k < 6; ++k) { C[k] = 0.f; S[k] = 0.f; }
        float slope = softplusf_(y[8]);

        #pragma unroll
        for (int m = 0; m < 2; ++m) {
            float p   = sigmoidf_(y[m]);
            float dst = sigmoidf_(y[2 + m]) * 2047.0f;            // delta*
            float sg  = 32.0f + sigmoidf_(y[4 + m]) * 224.0f;     // sigma
            float cm  = 0.01f * softplusf_(y[6 + m]);             // c
            float s2  = sg * sg;
            float a[6]; float asum = 0.f;
            #pragma unroll
            for (int k = 0; k < 6; ++k) { a[k] = expf(-0.5f * P.omg2[k] * s2); asum += a[k]; }
            float inv = 1.0f / (asum + 1e-9f);
            float pc  = p * cm;
            #pragma unroll
            for (int k = 0; k < 6; ++k) {
                float sn, cn;
                sincosf(P.omg[k] * dst, &sn, &cn);
                float amp = pc * (a[k] * inv);
                C[k] = fmaf(amp, cn, C[k]);
                S[k] = fmaf(amp, sn, S[k]);
            }
        }
        float b0 = 0.f;
        #pragma unroll
        for (int k = 0; k < 6; ++k) b0 += C[k] * P.cmn[k] + S[k] * P.smn[k];

        float* cf = ws + ((size_t)qid << 4);
        ((float4*)cf)[0] = make_float4(C[0], C[1], C[2], C[3]);
        ((float4*)cf)[1] = make_float4(C[4], C[5], S[0], S[1]);
        ((float4*)cf)[2] = make_float4(S[2], S[3], S[4], S[5]);
        ((float4*)cf)[3] = make_float4(b0, slope * (1.0f / 64.0f), 0.f, 0.f);
    }
}

// ---------------- Kernel 2: bias fill, one block per (h,i) row ----------------
// Thread t handles 8 consecutive j via a 2x2 phasor rotation per frequency.
__global__ __launch_bounds__(256) void sb_bias_kernel(
    const float* __restrict__ ws, float* __restrict__ out, BiasParams P)
{
    const int rid = blockIdx.x;        // h*2048 + i (uniform -> scalar loads below)
    const int i   = rid & 2047;
    const float* cf = ws + ((size_t)rid << 4);
    const float4 c0 = ((const float4*)cf)[0];
    const float4 c1 = ((const float4*)cf)[1];
    const float4 c2 = ((const float4*)cf)[2];
    const float4 c3 = ((const float4*)cf)[3];
    const float C[6] = {c0.x, c0.y, c0.z, c0.w, c1.x, c1.y};
    const float S[6] = {c1.z, c1.w, c2.x, c2.y, c2.z, c2.w};
    const float b0 = c3.x, slt = c3.y;

    const int j0 = threadIdx.x << 3;
    const int D0 = i - j0;             // Delta at first element (descends by 1 per step)
    float res[8];

    if (D0 < 0) {
        #pragma unroll
        for (int s = 0; s < 8; ++s) res[s] = 0.f;
    } else {
        // g_k = C cos(wD)+S sin(wD); h_k = S cos(wD)-C sin(wD); rotate to advance D -> D-1
        float g[6], hh[6];
        #pragma unroll
        for (int k = 0; k < 6; ++k) {
            float sn, cn;
            __sincosf(P.omg[k] * (float)D0, &sn, &cn);
            g[k]  = fmaf(C[k], cn,  S[k] * sn);
            hh[k] = fmaf(S[k], cn, -C[k] * sn);
        }
        float e = fmaf(-slt, (float)D0, -b0);   // res = sum_k g_k + e;  e += slt per step
        if (D0 >= 7) {
            // fully interior: no mask select
            #pragma unroll
            for (int s = 0; s < 8; ++s) {
                res[s] = (((g[0] + g[1]) + (g[2] + g[3])) + (g[4] + g[5])) + e;
                e += slt;
                #pragma unroll
                for (int k = 0; k < 6; ++k) {
                    float gn = fmaf(g[k],  P.cw[k], -hh[k] * P.sw[k]);
                    float hn = fmaf(hh[k], P.cw[k],  g[k]  * P.sw[k]);
                    g[k] = gn; hh[k] = hn;
                }
            }
        } else {
            #pragma unroll
            for (int s = 0; s < 8; ++s) {
                float four = ((g[0] + g[1]) + (g[2] + g[3])) + (g[4] + g[5]);
                res[s] = (s <= D0) ? (four + e) : 0.f;
                e += slt;
                #pragma unroll
                for (int k = 0; k < 6; ++k) {
                    float gn = fmaf(g[k],  P.cw[k], -hh[k] * P.sw[k]);
                    float hn = fmaf(hh[k], P.cw[k],  g[k]  * P.sw[k]);
                    g[k] = gn; hh[k] = hn;
                }
            }
        }
    }
    f32x4_* op = (f32x4_*)(out + (((size_t)rid) << 11) + j0);
    f32x4_ v0 = {res[0], res[1], res[2], res[3]};
    f32x4_ v1 = {res[4], res[5], res[6], res[7]};
    __builtin_nontemporal_store(v0, op + 0);
    __builtin_nontemporal_store(v1, op + 1);
}

extern "C" void kernel_launch(void* const* d_in, const int* in_sizes, int n_in,
                              void* d_out, int out_size, void* d_ws, size_t ws_size,
                              hipStream_t stream) {
    const float* q  = (const float*)d_in[0];
    const float* w1 = (const float*)d_in[1];
    const float* b1 = (const float*)d_in[2];
    const float* w2 = (const float*)d_in[3];
    const float* b2 = (const float*)d_in[4];
    float* out = (float*)d_out;
    float* ws  = (float*)d_ws;

    BiasParams P;
    const double l0 = log10(2.0 * M_PI / 1.0e6);     // log10(w_min)
    const double l1 = log10(2.0 * M_PI / 2048.0);    // log10(w_max)
    for (int k = 0; k < 6; ++k) {
        double e  = l0 + (l1 - l0) * ((double)k / 5.0);
        float  wf = (float)pow(10.0, e);             // matches np.logspace(...).astype(f32)
        P.omg[k]  = wf;
        P.omg2[k] = wf * wf;
        P.cw[k]   = (float)cos((double)wf);
        P.sw[k]   = (float)sin((double)wf);
        double cm = 0.0, sm = 0.0;
        for (int d = 0; d < 2048; ++d) { cm += cos((double)wf * d); sm += sin((double)wf * d); }
        P.cmn[k] = (float)(cm / 2048.0);
        P.smn[k] = (float)(sm / 2048.0);
    }

    sb_coef_kernel<<<512, 256, 0, stream>>>(q, w1, b1, w2, b2, ws, P);
    sb_bias_kernel<<<16 * 2048, 256, 0, stream>>>(ws, out, P);
}

// Round 4
// 309.160 us; speedup vs baseline: 1.2487x; 1.2487x over previous
//
#include <hip/hip_runtime.h>
#include <math.h>

// SpectralBias: B=1,H=16,L=2048,DH=64, M=2 modes, K=6 freqs, HIDDEN=128, OUT=9
// out[h,i,j] = mask(i>=j) * ( sum_k C[h,i,k] cos(w_k (i-j)) + S[h,i,k] sin(w_k (i-j))
//                             - b0[h,i] - slope[h,i]/64 * (i-j) )

struct BiasParams {
    float omg[6];   // omega_k (np.logspace(..).astype(f32))
    float omg2[6];  // omega_k^2
    float cw[6];    // cos(omega_k)
    float sw[6];    // sin(omega_k)
    float cmn[6];   // mean_d cos(omega_k d), d in [0,2048)  (host, double prec)
    float smn[6];   // mean_d sin(omega_k d)
};

__device__ __forceinline__ float sigmoidf_(float x) { return 1.0f / (1.0f + expf(-x)); }
__device__ __forceinline__ float softplusf_(float x) {
    return fmaxf(x, 0.0f) + log1pf(expf(-fabsf(x)));   // stable, matches jax.nn.softplus
}

// ---------------- Kernel 1: per-query MLP -> {C[6], S[6], b0, slope/64} ----------------
// 512 blocks x 256 threads; 64 queries/block (lane = query), wave w owns hidden [32w,32w+32).
// w1/b1/w2 are read at wave-uniform addresses -> scalar loads; q lives in 64 VGPRs.
__global__ __launch_bounds__(256) void sb_coef_kernel(
    const float* __restrict__ q,  const float* __restrict__ w1,
    const float* __restrict__ b1, const float* __restrict__ w2,
    const float* __restrict__ b2, float* __restrict__ ws, BiasParams P)
{
    __shared__ float pl[256 * 13];     // layer-2 partials [4 waves][64 q][13]
    const int t    = threadIdx.x;
    const int lane = t & 63;
    const int w    = t >> 6;
    const int qid  = (blockIdx.x << 6) + lane;

    // per-lane query row -> registers
    float qv[64];
    {
        const float4* qr = (const float4*)(q + ((size_t)qid << 6));
        #pragma unroll
        for (int j = 0; j < 16; ++j) {
            float4 v = qr[j];
            qv[4*j+0] = v.x; qv[4*j+1] = v.y; qv[4*j+2] = v.z; qv[4*j+3] = v.w;
        }
    }

    const int h0 = __builtin_amdgcn_readfirstlane(w << 5);   // wave-uniform
    const float* __restrict__ w1u = w1 + (size_t)h0 * 64;

    float part[9];
    #pragma unroll
    for (int o = 0; o < 9; ++o) part[o] = 0.f;

    #pragma unroll 4
    for (int h = 0; h < 32; ++h) {
        const float* __restrict__ wr = w1u + h * 64;         // uniform row
        float a0 = 0.f, a1 = 0.f, a2 = 0.f, a3 = 0.f;
        #pragma unroll
        for (int d = 0; d < 64; d += 4) {
            a0 = fmaf(qv[d+0], wr[d+0], a0);
            a1 = fmaf(qv[d+1], wr[d+1], a1);
            a2 = fmaf(qv[d+2], wr[d+2], a2);
            a3 = fmaf(qv[d+3], wr[d+3], a3);
        }
        float a = ((a0 + a1) + (a2 + a3)) + b1[h0 + h];
        a = a * sigmoidf_(a);                                // SiLU
        #pragma unroll
        for (int o = 0; o < 9; ++o)
            part[o] = fmaf(a, w2[o * 128 + h0 + h], part[o]); // uniform scalar
    }

    #pragma unroll
    for (int o = 0; o < 9; ++o) pl[t * 13 + o] = part[o];    // stride 13: conflict-free
    __syncthreads();

    if (w == 0) {
        float y[9];
        #pragma unroll
        for (int o = 0; o < 9; ++o)
            y[o] = b2[o] + pl[lane * 13 + o] + pl[(64 + lane) * 13 + o]
                 + pl[(128 + lane) * 13 + o] + pl[(192 + lane) * 13 + o];

        float C[6], S[6];
        #pragma unroll
        for (int k = 0; k < 6; ++k) { C[k] = 0.f; S[k] = 0.f; }
        float slope = softplusf_(y[8]);

        #pragma unroll
        for (int m = 0; m < 2; ++m) {
            float p   = sigmoidf_(y[m]);
            float dst = sigmoidf_(y[2 + m]) * 2047.0f;            // delta*
            float sg  = 32.0f + sigmoidf_(y[4 + m]) * 224.0f;     // sigma
            float cm  = 0.01f * softplusf_(y[6 + m]);             // c
            float s2  = sg * sg;
            float a[6]; float asum = 0.f;
            #pragma unroll
            for (int k = 0; k < 6; ++k) { a[k] = expf(-0.5f * P.omg2[k] * s2); asum += a[k]; }
            float inv = 1.0f / (asum + 1e-9f);
            float pc  = p * cm;
            #pragma unroll
            for (int k = 0; k < 6; ++k) {
                float sn, cn;
                sincosf(P.omg[k] * dst, &sn, &cn);
                float amp = pc * (a[k] * inv);
                C[k] = fmaf(amp, cn, C[k]);
                S[k] = fmaf(amp, sn, S[k]);
            }
        }
        float b0 = 0.f;
        #pragma unroll
        for (int k = 0; k < 6; ++k) b0 += C[k] * P.cmn[k] + S[k] * P.smn[k];

        float* cf = ws + ((size_t)qid << 4);
        ((float4*)cf)[0] = make_float4(C[0], C[1], C[2], C[3]);
        ((float4*)cf)[1] = make_float4(C[4], C[5], S[0], S[1]);
        ((float4*)cf)[2] = make_float4(S[2], S[3], S[4], S[5]);
        ((float4*)cf)[3] = make_float4(b0, slope * (1.0f / 64.0f), 0.f, 0.f);
    }
}

// ---------------- Kernel 2: bias fill, one block per (h,i) row ----------------
// Thread t handles 8 consecutive j via a 2x2 phasor rotation per frequency.
// Plain (cached) stores: 256MB output fits the 256MiB L3; kernel completes at
// L2/L3 write speed, write-back to HBM overlaps the next dispatches.
__global__ __launch_bounds__(256) void sb_bias_kernel(
    const float* __restrict__ ws, float* __restrict__ out, BiasParams P)
{
    const int rid = blockIdx.x;        // h*2048 + i (uniform -> scalar loads below)
    const int i   = rid & 2047;
    const float* cf = ws + ((size_t)rid << 4);
    const float4 c0 = ((const float4*)cf)[0];
    const float4 c1 = ((const float4*)cf)[1];
    const float4 c2 = ((const float4*)cf)[2];
    const float4 c3 = ((const float4*)cf)[3];
    const float C[6] = {c0.x, c0.y, c0.z, c0.w, c1.x, c1.y};
    const float S[6] = {c1.z, c1.w, c2.x, c2.y, c2.z, c2.w};
    const float b0 = c3.x, slt = c3.y;

    const int j0 = threadIdx.x << 3;
    const int D0 = i - j0;             // Delta at first element (descends by 1 per step)
    float res[8];

    if (D0 < 0) {
        #pragma unroll
        for (int s = 0; s < 8; ++s) res[s] = 0.f;
    } else {
        // g_k = C cos(wD)+S sin(wD); h_k = S cos(wD)-C sin(wD); rotate to advance D -> D-1
        float g[6], hh[6];
        #pragma unroll
        for (int k = 0; k < 6; ++k) {
            float sn, cn;
            __sincosf(P.omg[k] * (float)D0, &sn, &cn);
            g[k]  = fmaf(C[k], cn,  S[k] * sn);
            hh[k] = fmaf(S[k], cn, -C[k] * sn);
        }
        float e = fmaf(-slt, (float)D0, -b0);   // res = sum_k g_k + e;  e += slt per step
        if (D0 >= 7) {
            // fully interior: no mask select
            #pragma unroll
            for (int s = 0; s < 8; ++s) {
                res[s] = (((g[0] + g[1]) + (g[2] + g[3])) + (g[4] + g[5])) + e;
                e += slt;
                #pragma unroll
                for (int k = 0; k < 6; ++k) {
                    float gn = fmaf(g[k],  P.cw[k], -hh[k] * P.sw[k]);
                    float hn = fmaf(hh[k], P.cw[k],  g[k]  * P.sw[k]);
                    g[k] = gn; hh[k] = hn;
                }
            }
        } else {
            #pragma unroll
            for (int s = 0; s < 8; ++s) {
                float four = ((g[0] + g[1]) + (g[2] + g[3])) + (g[4] + g[5]);
                res[s] = (s <= D0) ? (four + e) : 0.f;
                e += slt;
                #pragma unroll
                for (int k = 0; k < 6; ++k) {
                    float gn = fmaf(g[k],  P.cw[k], -hh[k] * P.sw[k]);
                    float hn = fmaf(hh[k], P.cw[k],  g[k]  * P.sw[k]);
                    g[k] = gn; hh[k] = hn;
                }
            }
        }
    }
    float4* op = (float4*)(out + (((size_t)rid) << 11) + j0);
    op[0] = make_float4(res[0], res[1], res[2], res[3]);
    op[1] = make_float4(res[4], res[5], res[6], res[7]);
}

extern "C" void kernel_launch(void* const* d_in, const int* in_sizes, int n_in,
                              void* d_out, int out_size, void* d_ws, size_t ws_size,
                              hipStream_t stream) {
    const float* q  = (const float*)d_in[0];
    const float* w1 = (const float*)d_in[1];
    const float* b1 = (const float*)d_in[2];
    const float* w2 = (const float*)d_in[3];
    const float* b2 = (const float*)d_in[4];
    float* out = (float*)d_out;
    float* ws  = (float*)d_ws;

    BiasParams P;
    const double l0 = log10(2.0 * M_PI / 1.0e6);     // log10(w_min)
    const double l1 = log10(2.0 * M_PI / 2048.0);    // log10(w_max)
    for (int k = 0; k < 6; ++k) {
        double e  = l0 + (l1 - l0) * ((double)k / 5.0);
        float  wf = (float)pow(10.0, e);             // matches np.logspace(...).astype(f32)
        P.omg[k]  = wf;
        P.omg2[k] = wf * wf;
        P.cw[k]   = (float)cos((double)wf);
        P.sw[k]   = (float)sin((double)wf);
        double cm = 0.0, sm = 0.0;
        for (int d = 0; d < 2048; ++d) { cm += cos((double)wf * d); sm += sin((double)wf * d); }
        P.cmn[k] = (float)(cm / 2048.0);
        P.smn[k] = (float)(sm / 2048.0);
    }

    sb_coef_kernel<<<512, 256, 0, stream>>>(q, w1, b1, w2, b2, ws, P);
    sb_bias_kernel<<<16 * 2048, 256, 0, stream>>>(ws, out, P);
}